// Round 13
// baseline (575.989 us; speedup 1.0000x reference)
//
#include <hip/hip_runtime.h>
#include <math.h>

#define TOK   8192
#define DDIM  1024
#define HDIM  4096
#define NEXP  8
#define CAP   18432   /* 16384 + 8*256 pad = 72*256 = 144*128 */

typedef __attribute__((ext_vector_type(8))) short  bfrag;
typedef __attribute__((ext_vector_type(4))) float  ffrag;
typedef __attribute__((ext_vector_type(8))) unsigned short us8;

__device__ __forceinline__ unsigned short f2bf(float f) {
  unsigned int u = __float_as_uint(f);
  u = (u + 0x7FFFu + ((u >> 16) & 1u)) >> 16;   // RNE
  return (unsigned short)u;
}
__device__ __forceinline__ float bf2f(unsigned short u) {
  return __uint_as_float((unsigned int)u << 16);
}

__device__ __forceinline__ void gll16(const void* g, void* l) {
  __builtin_amdgcn_global_load_lds(
      (const __attribute__((address_space(1))) unsigned int*)g,
      (__attribute__((address_space(3))) unsigned int*)l,
      16, 0, 0);
}

// ---- transpose+cvt v5 (r12, unchanged): blocked output + 2-round prefetch ----
__global__ __launch_bounds__(256) void transpose_v5(const float* __restrict__ W1,
                                                    unsigned short* __restrict__ w1b,
                                                    const float* __restrict__ W2,
                                                    unsigned short* __restrict__ w2b) {
  int orig = blockIdx.x;
  int bid = (orig & 7) * 256 + (orig >> 3);
  const float* in; unsigned short* out; int R, C, tile;
  if (bid < 1024) { in = W1; out = w1b; R = DDIM; C = HDIM; tile = bid; }
  else            { in = W2; out = w2b; R = HDIM; C = DDIM; tile = bid - 1024; }
  int e = tile >> 7;
  int t = tile & 127;
  int tpr = C >> 8;
  int ty = t / tpr, tx = t % tpr;
  size_t bo = (size_t)e * R * C;
  in += bo; out += bo;
  int r0 = ty * 128, c0 = tx * 256;

  __shared__ __align__(16) float T[64 * 68];
  int tid = threadIdx.x;
  int r4 = (tid >> 4) * 4;
  int c4 = (tid & 15) * 4;
  int oc = tid >> 2;
  int kg = (tid & 3) * 16;

  auto ld = [&](int s, float4* v) {
    int rb = r0 + (s >> 2) * 64;
    int cb = c0 + (s & 3) * 64;
    v[0] = *(const float4*)&in[(size_t)(rb + r4 + 0) * C + cb + c4];
    v[1] = *(const float4*)&in[(size_t)(rb + r4 + 1) * C + cb + c4];
    v[2] = *(const float4*)&in[(size_t)(rb + r4 + 2) * C + cb + c4];
    v[3] = *(const float4*)&in[(size_t)(rb + r4 + 3) * C + cb + c4];
  };

  float4 v[4], nv[4];
  ld(0, v);
#pragma unroll
  for (int s = 0; s < 8; ++s) {
    if (s + 1 < 8) ld(s + 1, nv);
    int rb = r0 + (s >> 2) * 64;
    int cb = c0 + (s & 3) * 64;
    float4 t0 = { v[0].x, v[1].x, v[2].x, v[3].x };
    float4 t1 = { v[0].y, v[1].y, v[2].y, v[3].y };
    float4 t2 = { v[0].z, v[1].z, v[2].z, v[3].z };
    float4 t3 = { v[0].w, v[1].w, v[2].w, v[3].w };
    *(float4*)&T[(c4 + 0) * 68 + r4] = t0;
    *(float4*)&T[(c4 + 1) * 68 + r4] = t1;
    *(float4*)&T[(c4 + 2) * 68 + r4] = t2;
    *(float4*)&T[(c4 + 3) * 68 + r4] = t3;
    __syncthreads();
    float4 f0 = *(const float4*)&T[oc * 68 + kg + 0];
    float4 f1 = *(const float4*)&T[oc * 68 + kg + 4];
    float4 f2 = *(const float4*)&T[oc * 68 + kg + 8];
    float4 f3 = *(const float4*)&T[oc * 68 + kg + 12];
    us8 a, b;
    a[0] = (short)f2bf(f0.x); a[1] = (short)f2bf(f0.y);
    a[2] = (short)f2bf(f0.z); a[3] = (short)f2bf(f0.w);
    a[4] = (short)f2bf(f1.x); a[5] = (short)f2bf(f1.y);
    a[6] = (short)f2bf(f1.z); a[7] = (short)f2bf(f1.w);
    b[0] = (short)f2bf(f2.x); b[1] = (short)f2bf(f2.y);
    b[2] = (short)f2bf(f2.z); b[3] = (short)f2bf(f2.w);
    b[4] = (short)f2bf(f3.x); b[5] = (short)f2bf(f3.y);
    b[6] = (short)f2bf(f3.z); b[7] = (short)f2bf(f3.w);
    size_t sub = ((size_t)(cb >> 6) * (R >> 6) + (rb >> 6)) * 4096;
    *(us8*)&out[sub + oc * 64 + kg + 0] = a;
    *(us8*)&out[sub + oc * 64 + kg + 8] = b;
    __syncthreads();
    v[0] = nv[0]; v[1] = nv[1]; v[2] = nv[2]; v[3] = nv[3];
  }
}

// ---- gate v3 (r12, unchanged) ----
__global__ __launch_bounds__(256) void gate_v3(const float* __restrict__ x,
                                               const float* __restrict__ Wg,
                                               const float* __restrict__ bg,
                                               unsigned short* __restrict__ xb,
                                               int* __restrict__ topi,
                                               float* __restrict__ topw,
                                               int* __restrict__ cnt,
                                               int* __restrict__ token_of) {
  __shared__ int hist[NEXP];
  int tid = threadIdx.x;
  if (tid < NEXP) hist[tid] = 0;
  int gid = blockIdx.x * 256 + tid;
  if (gid < CAP) token_of[gid] = -1;
  __syncthreads();

  int w = tid >> 6, l = tid & 63;
  const float4* wg4 = (const float4*)Wg;
#pragma unroll 1
  for (int ti = 0; ti < 8; ++ti) {
    int t = (blockIdx.x * 4 + w) * 8 + ti;
    const float4* xr = (const float4*)(x + (size_t)t * DDIM);
    float acc[8];
#pragma unroll
    for (int e = 0; e < 8; ++e) acc[e] = 0.f;
#pragma unroll
    for (int gi = 0; gi < 2; ++gi) {
      int f = gi * 128 + 2 * l;
      float4 a0 = xr[f], a1 = xr[f + 1];
      us8 o;
      o[0] = (short)f2bf(a0.x); o[1] = (short)f2bf(a0.y);
      o[2] = (short)f2bf(a0.z); o[3] = (short)f2bf(a0.w);
      o[4] = (short)f2bf(a1.x); o[5] = (short)f2bf(a1.y);
      o[6] = (short)f2bf(a1.z); o[7] = (short)f2bf(a1.w);
      *(us8*)&xb[(size_t)t * DDIM + f * 4] = o;
      float xs[8] = { a0.x, a0.y, a0.z, a0.w, a1.x, a1.y, a1.z, a1.w };
      int dbase = f * 4;
#pragma unroll
      for (int c = 0; c < 8; ++c) {
        float4 w0 = wg4[(dbase + c) * 2 + 0];
        float4 w1 = wg4[(dbase + c) * 2 + 1];
        acc[0] += xs[c] * w0.x; acc[1] += xs[c] * w0.y;
        acc[2] += xs[c] * w0.z; acc[3] += xs[c] * w0.w;
        acc[4] += xs[c] * w1.x; acc[5] += xs[c] * w1.y;
        acc[6] += xs[c] * w1.z; acc[7] += xs[c] * w1.w;
      }
    }
#pragma unroll
    for (int off = 32; off >= 1; off >>= 1)
#pragma unroll
      for (int e = 0; e < 8; ++e) acc[e] += __shfl_down(acc[e], off);
    if (l == 0) {
      float v[8];
#pragma unroll
      for (int e = 0; e < 8; ++e) v[e] = acc[e] + bg[e];
      int i0 = 0;
#pragma unroll
      for (int e = 1; e < 8; ++e) if (v[e] > v[i0]) i0 = e;
      int i1 = -1;
#pragma unroll
      for (int e = 0; e < 8; ++e) if (e != i0 && (i1 < 0 || v[e] > v[i1])) i1 = e;
      float e1 = expf(v[i1] - v[i0]);
      float s = 1.f + e1;
      topi[t * 2 + 0] = i0; topi[t * 2 + 1] = i1;
      topw[t * 2 + 0] = 1.f / s; topw[t * 2 + 1] = e1 / s;
      atomicAdd(&hist[i0], 1);
      atomicAdd(&hist[i1], 1);
    }
  }
  __syncthreads();
  if (tid < NEXP) atomicAdd(&cnt[tid], hist[tid]);
}

// 256-aligned exclusive scan of cnt (shared by both GEMMs and assign)
__device__ __forceinline__ void local_scan(const int* __restrict__ cnt, int* offs) {
  int o = 0;
#pragma unroll
  for (int e = 0; e < NEXP; ++e) {
    offs[e] = o;
    o += ((cnt[e] + 255) >> 8) << 8;
  }
  offs[NEXP] = o;
}

__global__ __launch_bounds__(256) void assign_kernel(const int* __restrict__ topi,
                                                     const int* __restrict__ cnt,
                                                     int* __restrict__ cursor,
                                                     int* __restrict__ row_of,
                                                     int* __restrict__ token_of) {
  int offs[NEXP + 1];
  local_scan(cnt, offs);
  int id = blockIdx.x * 256 + threadIdx.x;
  if (id >= TOK * 2) return;
  int e = topi[id];
  int slot = atomicAdd(&cursor[e], 1);
  int row = offs[e] + slot;
  row_of[id] = row;
  token_of[row] = id >> 1;
}

// ---- GEMM1 (r12 structure, unchanged): 128^2, 3-buf counted-vmcnt, blocked B ----
template<bool INDIRECT, bool GELU>
__global__ __launch_bounds__(256)
void moe_gemm(const unsigned short* __restrict__ A,
              const unsigned short* __restrict__ B0,
              const float* __restrict__ bias0,
              unsigned short* __restrict__ out,
              int N, int K,
              const int* __restrict__ cnt,
              const int* __restrict__ token_of) {
  int offsets[NEXP + 1];
  local_scan(cnt, offsets);

  int nwg = gridDim.x * gridDim.y;
  int orig = blockIdx.y * gridDim.x + blockIdx.x;
  int V = nwg >> 3;
  int vid = (orig & 7) * V + (orig >> 3);
  int xcd = vid / V;
  int vloc = vid - xcd * V;
  int P = V / gridDim.x;
  int CW = gridDim.x >= 8 ? 8 : gridDim.x;
  int per = P * CW;
  int g = vloc / per;
  int rem = vloc - g * per;
  int m = rem / CW;
  int bx = g * CW + (rem - m * CW);
  int by = xcd * P + m;

  int row0 = by * 128;
  if (row0 >= offsets[NEXP]) return;
  int e = 0;
  while (row0 >= offsets[e + 1]) ++e;
  const unsigned short* B = B0 + (size_t)e * N * K;
  const float* bias = bias0 + (size_t)e * N;
  int n0 = bx * 128;

  __shared__ __align__(16) char sm[49152];

  int tid = threadIdx.x;
  int w = tid >> 6, l = tid & 63;
  int lrow = l & 15, kq = l >> 4;
  int wm = w >> 1, wn = w & 1;

  int c2 = (l & 7) ^ (l >> 3);
  int rloc = ((l >> 3) << 1) + (c2 >> 2);
  int ksw = (c2 & 3) * 16;
  int s0 = 2 * w, s1 = 2 * w + 1;

  int gr0 = row0 + s0 * 16 + rloc, gr1 = row0 + s1 * 16 + rloc;
  int ar0, ar1;
  if (INDIRECT) {
    int t0 = token_of[gr0]; ar0 = t0 < 0 ? 0 : t0;
    int t1 = token_of[gr1]; ar1 = t1 < 0 ? 0 : t1;
  } else { ar0 = gr0; ar1 = gr1; }
  const char* srcA0 = (const char*)(A + (size_t)ar0 * K) + ksw;
  const char* srcA1 = (const char*)(A + (size_t)ar1 * K) + ksw;
  auto bsrc = [&](int nloc) -> const char* {
    int n = n0 + nloc;
    return (const char*)B + ((size_t)(n >> 6) * (K >> 6)) * 8192 + (n & 63) * 128 + ksw;
  };
  const char* srcB0 = bsrc(s0 * 16 + rloc);
  const char* srcB1 = bsrc(s1 * 16 + rloc);

  auto stage = [&](int buf, int k0) {
    int kbA = k0 * 2;
    int kbB = (k0 >> 6) * 8192 + (k0 & 63) * 2;
    gll16(srcA0 + kbA, sm + buf * 8192 + s0 * 1024);
    gll16(srcA1 + kbA, sm + buf * 8192 + s1 * 1024);
    gll16(srcB0 + kbB, sm + 24576 + buf * 8192 + s0 * 1024);
    gll16(srcB1 + kbB, sm + 24576 + buf * 8192 + s1 * 1024);
  };

  int offA[4], offB[4];
#pragma unroll
  for (int i = 0; i < 4; ++i) {
    int ra = wm * 64 + i * 16 + lrow;
    offA[i] = (ra >> 1) * 128 + (((((ra & 1) << 2) + kq) ^ ((ra >> 1) & 7)) << 4);
    int rb = wn * 64 + i * 16 + lrow;
    offB[i] = 24576 + (rb >> 1) * 128 + (((((rb & 1) << 2) + kq) ^ ((rb >> 1) & 7)) << 4);
  }

  ffrag acc[4][4];
#pragma unroll
  for (int i = 0; i < 4; ++i)
#pragma unroll
    for (int j = 0; j < 4; ++j) acc[i][j] = (ffrag){0.f, 0.f, 0.f, 0.f};

  auto compute = [&](int buf) {
    int ab = buf * 8192;
    bfrag a[4], b[4];
#pragma unroll
    for (int i = 0; i < 4; ++i) a[i] = *(const bfrag*)(sm + ab + offA[i]);
#pragma unroll
    for (int j = 0; j < 4; ++j) b[j] = *(const bfrag*)(sm + ab + offB[j]);
#pragma unroll
    for (int i = 0; i < 4; ++i)
#pragma unroll
      for (int j = 0; j < 4; ++j)
        acc[i][j] = __builtin_amdgcn_mfma_f32_16x16x32_bf16(a[i], b[j], acc[i][j], 0, 0, 0);
  };

  stage(0, 0); stage(1, 32);
  asm volatile("s_waitcnt vmcnt(4)" ::: "memory");
  __builtin_amdgcn_s_barrier();

  int nk = K / 32;
  int cur = 0;
  for (int kt = 0; kt < nk; ++kt) {
    int nxt2 = cur + 2; if (nxt2 >= 3) nxt2 -= 3;
    if (kt + 2 < nk) stage(nxt2, (kt + 2) * 32);
    compute(cur);
    if (kt + 1 < nk) {
      if (kt + 2 < nk) { asm volatile("s_waitcnt vmcnt(4)" ::: "memory"); }
      else             { asm volatile("s_waitcnt vmcnt(0)" ::: "memory"); }
    }
    __builtin_amdgcn_s_barrier();
    ++cur; if (cur == 3) cur = 0;
  }

  unsigned short* ht = (unsigned short*)sm;
#pragma unroll
  for (int j = 0; j < 4; ++j) {
    int col = wn * 64 + j * 16 + lrow;
    float bj = bias[n0 + col];
#pragma unroll
    for (int i = 0; i < 4; ++i) {
      int rl = wm * 64 + i * 16 + kq * 4;
#pragma unroll
      for (int r = 0; r < 4; ++r) {
        float v = acc[i][j][r] + bj;
        if (GELU) {
          float z = 1.5957691216f * (v + 0.044715f * v * v * v);
          v = v / (1.0f + __expf(-z));
        }
        ht[(rl + r) * 128 + col] = f2bf(v);
      }
    }
  }
  __syncthreads();
#pragma unroll
  for (int it = 0; it < 8; ++it) {
    int c = it * 256 + tid;
    int row = c >> 4;
    int cc = (c & 15) * 8;
    us8 v = *(const us8*)&ht[row * 128 + cc];
    *(us8*)&out[(size_t)(row0 + row) * N + n0 + cc] = v;
  }
}

// ---- GEMM2: 256^2, BK=64, 4-quadrant phases, deep counted-vmcnt (8-phase/2-tile) ----
// A = h [CAP][K] direct rows; B blocked [e][ntile][ktile][64n][64k]; y bf16 out.
// Half-tiles: A-half h = rows bit6==h; B-half h = cols bit5==h. One half staged
// per phase in first-use order (A0,B0,B1,A1), used one tile later (3-4 phase
// flight); waits vmcnt(4) at P0/P1/P2 leave >=4 loads in flight, never drain.
__global__ __launch_bounds__(512)
void moe_gemm2(const unsigned short* __restrict__ A,
               const unsigned short* __restrict__ B0,
               const float* __restrict__ bias0,
               unsigned short* __restrict__ y,
               const int* __restrict__ cnt) {
  constexpr int N = DDIM, K = HDIM;
  int offs[NEXP + 1];
  local_scan(cnt, offs);

  int nwg = gridDim.x * gridDim.y;          // 288
  int orig = blockIdx.y * gridDim.x + blockIdx.x;
  int V = nwg >> 3;                          // 36
  int vid = (orig & 7) * V + (orig >> 3);
  int bx = vid & 3, by = vid >> 2;           // gridDim.x == 4

  int row0 = by * 256;
  if (row0 >= offs[NEXP]) return;
  int e = 0;
  while (row0 >= offs[e + 1]) ++e;
  const unsigned short* B = B0 + (size_t)e * N * K;
  const float* bias = bias0 + (size_t)e * N;
  int n0 = bx * 256;

  __shared__ __align__(16) char sm[131072];  // A: [2buf][2half][16KB], B at +64K

  int tid = threadIdx.x;
  int w = tid >> 6, l = tid & 63;
  int lrow = l & 15, kq = l >> 4;
  int wm = w & 1, wn = w >> 1;               // per-wave C = 128 rows x 64 cols

  int cg = (l & 7) ^ (l >> 3);               // inverse-swizzled chunk col (0..7)

  // staging sources: half h2, load j
  const char* sA[2][2];
  const char* sB[2][2];
#pragma unroll
  for (int h2 = 0; h2 < 2; ++h2)
#pragma unroll
    for (int j = 0; j < 2; ++j) {
      int g = row0 + j * 128 + h2 * 64 + w * 8 + (l >> 3);
      sA[h2][j] = (const char*)A + (size_t)g * (K * 2) + cg * 16;
      int ntile = bx * 4 + j * 2 + (w >> 2);
      int nloc = h2 * 32 + (w & 3) * 8 + (l >> 3);
      sB[h2][j] = (const char*)B + ((size_t)ntile * (K >> 6)) * 8192 + nloc * 128 + cg * 16;
    }

  auto issueA = [&](int t, int h2) {
    int dst = (t & 1) * 32768 + h2 * 16384 + w * 1024 + l * 16;
    int kb = t * 128;
    gll16(sA[h2][0] + kb, sm + dst);
    gll16(sA[h2][1] + kb, sm + dst + 8192);
  };
  auto issueB = [&](int t, int h2) {
    int dst = 65536 + (t & 1) * 32768 + h2 * 16384 + w * 1024 + l * 16;
    int kb = t * 8192;
    gll16(sB[h2][0] + kb, sm + dst);
    gll16(sB[h2][1] + kb, sm + dst + 8192);
  };
  auto rdA = [&](int bufo, int qm, int i, int ks) -> bfrag {
    int r = wm * 64 + i * 16 + lrow;
    int cc = (ks * 4 + kq) ^ (r & 7);
    return *(const bfrag*)(sm + bufo + qm * 16384 + r * 128 + cc * 16);
  };
  auto rdB = [&](int bufo, int qn, int nj, int ks) -> bfrag {
    int r = wn * 32 + nj * 16 + lrow;
    int cc = (ks * 4 + kq) ^ (r & 7);
    return *(const bfrag*)(sm + 65536 + bufo + qn * 16384 + r * 128 + cc * 16);
  };

  ffrag acc[8][4];
#pragma unroll
  for (int i = 0; i < 8; ++i)
#pragma unroll
    for (int j = 0; j < 4; ++j) acc[i][j] = (ffrag){0.f, 0.f, 0.f, 0.f};

#define MFMA_Q(MO, NO)                                                           \
  __builtin_amdgcn_s_setprio(1);                                                 \
  _Pragma("unroll")                                                              \
  for (int i = 0; i < 4; ++i)                                                    \
    _Pragma("unroll")                                                            \
    for (int nj = 0; nj < 2; ++nj) {                                             \
      acc[i + MO][nj + NO] = __builtin_amdgcn_mfma_f32_16x16x32_bf16(            \
          a[i][0], b[nj][0], acc[i + MO][nj + NO], 0, 0, 0);                     \
      acc[i + MO][nj + NO] = __builtin_amdgcn_mfma_f32_16x16x32_bf16(            \
          a[i][1], b[nj][1], acc[i + MO][nj + NO], 0, 0, 0);                     \
    }                                                                            \
  __builtin_amdgcn_s_setprio(0);

  // prologue: tile 0 halves in first-use order
  issueA(0, 0); issueB(0, 0); issueB(0, 1); issueA(0, 1);

  const int NT = K / 64;                     // 64
  bfrag a[4][2], b[2][2];
#pragma unroll 1
  for (int t = 0; t < NT; ++t) {
    int bufo = (t & 1) * 32768;
    bool pre = (t + 1 < NT);
    // ---- P0: quad (qm=0,qn=0); needs A0(t),B0(t) = oldest 4 loads ----
    asm volatile("s_waitcnt vmcnt(4)" ::: "memory");
    __builtin_amdgcn_s_barrier();
#pragma unroll
    for (int i = 0; i < 4; ++i) { a[i][0] = rdA(bufo, 0, i, 0); a[i][1] = rdA(bufo, 0, i, 1); }
#pragma unroll
    for (int nj = 0; nj < 2; ++nj) { b[nj][0] = rdB(bufo, 0, nj, 0); b[nj][1] = rdB(bufo, 0, nj, 1); }
    if (pre) issueA(t + 1, 0);
    MFMA_Q(0, 0)
    // ---- P1: quad (0,1); needs B1(t) ----
    if (pre) { asm volatile("s_waitcnt vmcnt(4)" ::: "memory"); }
    else     { asm volatile("s_waitcnt vmcnt(2)" ::: "memory"); }
    __builtin_amdgcn_s_barrier();
#pragma unroll
    for (int nj = 0; nj < 2; ++nj) { b[nj][0] = rdB(bufo, 1, nj, 0); b[nj][1] = rdB(bufo, 1, nj, 1); }
    if (pre) issueB(t + 1, 0);
    MFMA_Q(0, 2)
    // ---- P2: quad (1,1); needs A1(t) ----
    if (pre) { asm volatile("s_waitcnt vmcnt(4)" ::: "memory"); }
    else     { asm volatile("s_waitcnt vmcnt(0)" ::: "memory"); }
    __builtin_amdgcn_s_barrier();
#pragma unroll
    for (int i = 0; i < 4; ++i) { a[i][0] = rdA(bufo, 1, i, 0); a[i][1] = rdA(bufo, 1, i, 1); }
    if (pre) issueB(t + 1, 1);
    MFMA_Q(4, 2)
    // ---- P3: quad (1,0); B0(t) already landed ----
    __builtin_amdgcn_s_barrier();
#pragma unroll
    for (int nj = 0; nj < 2; ++nj) { b[nj][0] = rdB(bufo, 0, nj, 0); b[nj][1] = rdB(bufo, 0, nj, 1); }
    if (pre) issueA(t + 1, 1);
    MFMA_Q(4, 0)
  }
#undef MFMA_Q

  // epilogue: bias, bf16, LDS-staged coalesced stores
  __syncthreads();
  unsigned short* ht = (unsigned short*)sm;   // [256][256] bf16
#pragma unroll
  for (int mi = 0; mi < 8; ++mi) {
    int rl = wm * 128 + (mi >> 2) * 64 + (mi & 3) * 16 + kq * 4;
#pragma unroll
    for (int nj = 0; nj < 4; ++nj) {
      int col = wn * 64 + (nj >> 1) * 32 + (nj & 1) * 16 + lrow;
      float bj = bias[n0 + col];
#pragma unroll
      for (int r = 0; r < 4; ++r)
        ht[(rl + r) * 256 + col] = f2bf(acc[mi][nj][r] + bj);
    }
  }
  __syncthreads();
#pragma unroll
  for (int it = 0; it < 16; ++it) {
    int s = it * 512 + tid;
    int row = s >> 5, c = (s & 31) * 8;
    us8 v = *(const us8*)(ht + row * 256 + c);
    *(us8*)&y[(size_t)(row0 + row) * N + n0 + c] = v;
  }
}

// ---------------- combine (y is bf16) ----------------
__global__ __launch_bounds__(256) void combine_kernel(const unsigned short* __restrict__ y,
                                                      const int* __restrict__ row_of,
                                                      const float* __restrict__ topw,
                                                      float* __restrict__ out) {
  int t = blockIdx.x;
  int r0 = row_of[t * 2 + 0], r1 = row_of[t * 2 + 1];
  float w0 = topw[t * 2 + 0], w1 = topw[t * 2 + 1];
  const ushort4* y0 = (const ushort4*)(y + (size_t)r0 * DDIM);
  const ushort4* y1 = (const ushort4*)(y + (size_t)r1 * DDIM);
  float4* o = (float4*)(out + (size_t)t * DDIM);
  int i = threadIdx.x;
  ushort4 a = y0[i], b = y1[i];
  float4 r = { w0 * bf2f(a.x) + w1 * bf2f(b.x), w0 * bf2f(a.y) + w1 * bf2f(b.y),
               w0 * bf2f(a.z) + w1 * bf2f(b.z), w0 * bf2f(a.w) + w1 * bf2f(b.w) };
  o[i] = r;
}

extern "C" void kernel_launch(void* const* d_in, const int* in_sizes, int n_in,
                              void* d_out, int out_size, void* d_ws, size_t ws_size,
                              hipStream_t stream) {
  const float* x  = (const float*)d_in[0];
  const float* Wg = (const float*)d_in[1];
  const float* bg = (const float*)d_in[2];
  const float* W1 = (const float*)d_in[3];
  const float* b1 = (const float*)d_in[4];
  const float* W2 = (const float*)d_in[5];
  const float* b2 = (const float*)d_in[6];
  float* out = (float*)d_out;

  size_t off = 0;
  char* base = (char*)d_ws;
  auto alloc = [&](size_t bytes) -> void* {
    void* p = base + off;
    off += (bytes + 255) & ~(size_t)255;
    return p;
  };
  unsigned short* xb  = (unsigned short*)alloc((size_t)TOK * DDIM * 2);
  unsigned short* w1b = (unsigned short*)alloc((size_t)NEXP * HDIM * DDIM * 2);
  unsigned short* w2b = (unsigned short*)alloc((size_t)NEXP * DDIM * HDIM * 2);
  unsigned short* h   = (unsigned short*)alloc((size_t)CAP * HDIM * 2);
  unsigned short* y   = (unsigned short*)alloc((size_t)CAP * DDIM * 2);
  int*   topi     = (int*)alloc((size_t)TOK * 2 * 4);
  float* topw     = (float*)alloc((size_t)TOK * 2 * 4);
  int*   row_of   = (int*)alloc((size_t)TOK * 2 * 4);
  int*   token_of = (int*)alloc((size_t)CAP * 4);
  int*   cntcur   = (int*)alloc(64);      // cnt = [0..7], cursor = [8..15]
  if (off > ws_size) return;

  int* cnt = cntcur;
  int* cursor = cntcur + 8;

  hipMemsetAsync(cntcur, 0, 64, stream);

  gate_v3<<<256, 256, 0, stream>>>(x, Wg, bg, xb, topi, topw, cnt, token_of);
  transpose_v5<<<2048, 256, 0, stream>>>(W1, w1b, W2, w2b);
  assign_kernel<<<(TOK * 2) / 256, 256, 0, stream>>>(topi, cnt, cursor,
                                                     row_of, token_of);

  moe_gemm<true, true><<<dim3(HDIM / 128, CAP / 128), 256, 0, stream>>>(
      xb, w1b, b1, h, HDIM, DDIM, cnt, token_of);
  moe_gemm2<<<dim3(DDIM / 256, CAP / 256), 512, 0, stream>>>(
      h, w2b, b2, y, cnt);

  combine_kernel<<<TOK, 256, 0, stream>>>(y, row_of, topw, out);
}

// Round 14
// 538.667 us; speedup vs baseline: 1.0693x; 1.0693x over previous
//
#include <hip/hip_runtime.h>
#include <math.h>

#define TOK   8192
#define DDIM  1024
#define HDIM  4096
#define NEXP  8
#define CAP   17408   /* 16384 + 8*128 pad = 136*128 */

typedef __attribute__((ext_vector_type(8))) short  bfrag;
typedef __attribute__((ext_vector_type(4))) float  ffrag;
typedef __attribute__((ext_vector_type(8))) unsigned short us8;

__device__ __forceinline__ unsigned short f2bf(float f) {
  unsigned int u = __float_as_uint(f);
  u = (u + 0x7FFFu + ((u >> 16) & 1u)) >> 16;   // RNE
  return (unsigned short)u;
}
__device__ __forceinline__ float bf2f(unsigned short u) {
  return __uint_as_float((unsigned int)u << 16);
}

__device__ __forceinline__ void gll16(const void* g, void* l) {
  __builtin_amdgcn_global_load_lds(
      (const __attribute__((address_space(1))) unsigned int*)g,
      (__attribute__((address_space(3))) unsigned int*)l,
      16, 0, 0);
}

// 128-aligned exclusive scan of cnt (uniform, 8 entries)
__device__ __forceinline__ void local_scan(const int* __restrict__ cnt, int* offs) {
  int o = 0;
#pragma unroll
  for (int e = 0; e < NEXP; ++e) {
    offs[e] = o;
    o += ((cnt[e] + 127) >> 7) << 7;
  }
  offs[NEXP] = o;
}

// ---- transpose+cvt v6: blocked output, 2-round reg prefetch, LDS double-buffer,
//      assign fused as trailing blocks (gate has completed -> cnt final) ----
__global__ __launch_bounds__(256)
void transpose_v6(const float* __restrict__ W1, unsigned short* __restrict__ w1b,
                  const float* __restrict__ W2, unsigned short* __restrict__ w2b,
                  const int* __restrict__ topi, const int* __restrict__ cnt,
                  int* __restrict__ cursor, int* __restrict__ row_of,
                  int* __restrict__ token_of) {
  if (blockIdx.x >= 2048) {
    // ---------------- assign path (64 blocks x 256 thr = 16384) ----------------
    int offs[NEXP + 1];
    local_scan(cnt, offs);
    int id = (blockIdx.x - 2048) * 256 + threadIdx.x;
    int e = topi[id];
    int slot = atomicAdd(&cursor[e], 1);
    int row = offs[e] + slot;
    row_of[id] = row;
    token_of[row] = id >> 1;
    return;
  }
  int orig = blockIdx.x;
  int bid = (orig & 7) * 256 + (orig >> 3);    // XCD-chunked, bijective
  const float* in; unsigned short* out; int R, C, tile;
  if (bid < 1024) { in = W1; out = w1b; R = DDIM; C = HDIM; tile = bid; }
  else            { in = W2; out = w2b; R = HDIM; C = DDIM; tile = bid - 1024; }
  int e = tile >> 7;
  int t = tile & 127;
  int tpr = C >> 8;
  int ty = t / tpr, tx = t % tpr;
  size_t bo = (size_t)e * R * C;
  in += bo; out += bo;
  int r0 = ty * 128, c0 = tx * 256;

  __shared__ __align__(16) float T[2 * 64 * 68];
  int tid = threadIdx.x;
  int r4 = (tid >> 4) * 4;
  int c4 = (tid & 15) * 4;
  int oc = tid >> 2;
  int kg = (tid & 3) * 16;

  auto ld = [&](int s, float4* v) {
    int rb = r0 + (s >> 2) * 64;
    int cb = c0 + (s & 3) * 64;
    v[0] = *(const float4*)&in[(size_t)(rb + r4 + 0) * C + cb + c4];
    v[1] = *(const float4*)&in[(size_t)(rb + r4 + 1) * C + cb + c4];
    v[2] = *(const float4*)&in[(size_t)(rb + r4 + 2) * C + cb + c4];
    v[3] = *(const float4*)&in[(size_t)(rb + r4 + 3) * C + cb + c4];
  };

  float4 v[4], nv[4];
  ld(0, v);
#pragma unroll
  for (int s = 0; s < 8; ++s) {
    if (s + 1 < 8) ld(s + 1, nv);
    float* Tb = T + (s & 1) * 4352;
    int rb = r0 + (s >> 2) * 64;
    int cb = c0 + (s & 3) * 64;
    float4 t0 = { v[0].x, v[1].x, v[2].x, v[3].x };
    float4 t1 = { v[0].y, v[1].y, v[2].y, v[3].y };
    float4 t2 = { v[0].z, v[1].z, v[2].z, v[3].z };
    float4 t3 = { v[0].w, v[1].w, v[2].w, v[3].w };
    *(float4*)&Tb[(c4 + 0) * 68 + r4] = t0;
    *(float4*)&Tb[(c4 + 1) * 68 + r4] = t1;
    *(float4*)&Tb[(c4 + 2) * 68 + r4] = t2;
    *(float4*)&Tb[(c4 + 3) * 68 + r4] = t3;
    __syncthreads();            // write(s) visible; also drains prior reads (lgkm)
    float4 f0 = *(const float4*)&Tb[oc * 68 + kg + 0];
    float4 f1 = *(const float4*)&Tb[oc * 68 + kg + 4];
    float4 f2 = *(const float4*)&Tb[oc * 68 + kg + 8];
    float4 f3 = *(const float4*)&Tb[oc * 68 + kg + 12];
    us8 a, b;
    a[0] = (short)f2bf(f0.x); a[1] = (short)f2bf(f0.y);
    a[2] = (short)f2bf(f0.z); a[3] = (short)f2bf(f0.w);
    a[4] = (short)f2bf(f1.x); a[5] = (short)f2bf(f1.y);
    a[6] = (short)f2bf(f1.z); a[7] = (short)f2bf(f1.w);
    b[0] = (short)f2bf(f2.x); b[1] = (short)f2bf(f2.y);
    b[2] = (short)f2bf(f2.z); b[3] = (short)f2bf(f2.w);
    b[4] = (short)f2bf(f3.x); b[5] = (short)f2bf(f3.y);
    b[6] = (short)f2bf(f3.z); b[7] = (short)f2bf(f3.w);
    size_t sub = ((size_t)(cb >> 6) * (R >> 6) + (rb >> 6)) * 4096;
    *(us8*)&out[sub + oc * 64 + kg + 0] = a;
    *(us8*)&out[sub + oc * 64 + kg + 8] = b;
    v[0] = nv[0]; v[1] = nv[1]; v[2] = nv[2]; v[3] = nv[3];
  }
}

// ---- gate v3 (r12, unchanged) ----
__global__ __launch_bounds__(256) void gate_v3(const float* __restrict__ x,
                                               const float* __restrict__ Wg,
                                               const float* __restrict__ bg,
                                               unsigned short* __restrict__ xb,
                                               int* __restrict__ topi,
                                               float* __restrict__ topw,
                                               int* __restrict__ cnt,
                                               int* __restrict__ token_of) {
  __shared__ int hist[NEXP];
  int tid = threadIdx.x;
  if (tid < NEXP) hist[tid] = 0;
  int gid = blockIdx.x * 256 + tid;
  if (gid < CAP) token_of[gid] = -1;
  __syncthreads();

  int w = tid >> 6, l = tid & 63;
  const float4* wg4 = (const float4*)Wg;
#pragma unroll 1
  for (int ti = 0; ti < 8; ++ti) {
    int t = (blockIdx.x * 4 + w) * 8 + ti;
    const float4* xr = (const float4*)(x + (size_t)t * DDIM);
    float acc[8];
#pragma unroll
    for (int e = 0; e < 8; ++e) acc[e] = 0.f;
#pragma unroll
    for (int gi = 0; gi < 2; ++gi) {
      int f = gi * 128 + 2 * l;
      float4 a0 = xr[f], a1 = xr[f + 1];
      us8 o;
      o[0] = (short)f2bf(a0.x); o[1] = (short)f2bf(a0.y);
      o[2] = (short)f2bf(a0.z); o[3] = (short)f2bf(a0.w);
      o[4] = (short)f2bf(a1.x); o[5] = (short)f2bf(a1.y);
      o[6] = (short)f2bf(a1.z); o[7] = (short)f2bf(a1.w);
      *(us8*)&xb[(size_t)t * DDIM + f * 4] = o;
      float xs[8] = { a0.x, a0.y, a0.z, a0.w, a1.x, a1.y, a1.z, a1.w };
      int dbase = f * 4;
#pragma unroll
      for (int c = 0; c < 8; ++c) {
        float4 w0 = wg4[(dbase + c) * 2 + 0];
        float4 w1 = wg4[(dbase + c) * 2 + 1];
        acc[0] += xs[c] * w0.x; acc[1] += xs[c] * w0.y;
        acc[2] += xs[c] * w0.z; acc[3] += xs[c] * w0.w;
        acc[4] += xs[c] * w1.x; acc[5] += xs[c] * w1.y;
        acc[6] += xs[c] * w1.z; acc[7] += xs[c] * w1.w;
      }
    }
#pragma unroll
    for (int off = 32; off >= 1; off >>= 1)
#pragma unroll
      for (int e = 0; e < 8; ++e) acc[e] += __shfl_down(acc[e], off);
    if (l == 0) {
      float v[8];
#pragma unroll
      for (int e = 0; e < 8; ++e) v[e] = acc[e] + bg[e];
      int i0 = 0;
#pragma unroll
      for (int e = 1; e < 8; ++e) if (v[e] > v[i0]) i0 = e;
      int i1 = -1;
#pragma unroll
      for (int e = 0; e < 8; ++e) if (e != i0 && (i1 < 0 || v[e] > v[i1])) i1 = e;
      float e1 = expf(v[i1] - v[i0]);
      float s = 1.f + e1;
      topi[t * 2 + 0] = i0; topi[t * 2 + 1] = i1;
      topw[t * 2 + 0] = 1.f / s; topw[t * 2 + 1] = e1 / s;
      atomicAdd(&hist[i0], 1);
      atomicAdd(&hist[i1], 1);
    }
  }
  __syncthreads();
  if (tid < NEXP) atomicAdd(&cnt[tid], hist[tid]);
}

// ---- grouped GEMM (r12 structure): 128^2, 3-buf counted-vmcnt, blocked B ----
template<bool INDIRECT, bool GELU>
__global__ __launch_bounds__(256)
void moe_gemm(const unsigned short* __restrict__ A,
              const unsigned short* __restrict__ B0,
              const float* __restrict__ bias0,
              unsigned short* __restrict__ out,
              int N, int K,
              const int* __restrict__ cnt,
              const int* __restrict__ token_of) {
  int offsets[NEXP + 1];
  local_scan(cnt, offsets);

  int nwg = gridDim.x * gridDim.y;
  int orig = blockIdx.y * gridDim.x + blockIdx.x;
  int V = nwg >> 3;
  int vid = (orig & 7) * V + (orig >> 3);
  int xcd = vid / V;
  int vloc = vid - xcd * V;
  int P = V / gridDim.x;
  int CW = gridDim.x >= 8 ? 8 : gridDim.x;
  int per = P * CW;
  int g = vloc / per;
  int rem = vloc - g * per;
  int m = rem / CW;
  int bx = g * CW + (rem - m * CW);
  int by = xcd * P + m;

  int row0 = by * 128;
  if (row0 >= offsets[NEXP]) return;
  int e = 0;
  while (row0 >= offsets[e + 1]) ++e;
  const unsigned short* B = B0 + (size_t)e * N * K;
  const float* bias = bias0 + (size_t)e * N;
  int n0 = bx * 128;

  __shared__ __align__(16) char sm[49152];

  int tid = threadIdx.x;
  int w = tid >> 6, l = tid & 63;
  int lrow = l & 15, kq = l >> 4;
  int wm = w >> 1, wn = w & 1;

  int c2 = (l & 7) ^ (l >> 3);
  int rloc = ((l >> 3) << 1) + (c2 >> 2);
  int ksw = (c2 & 3) * 16;
  int s0 = 2 * w, s1 = 2 * w + 1;

  int gr0 = row0 + s0 * 16 + rloc, gr1 = row0 + s1 * 16 + rloc;
  int ar0, ar1;
  if (INDIRECT) {
    int t0 = token_of[gr0]; ar0 = t0 < 0 ? 0 : t0;
    int t1 = token_of[gr1]; ar1 = t1 < 0 ? 0 : t1;
  } else { ar0 = gr0; ar1 = gr1; }
  const char* srcA0 = (const char*)(A + (size_t)ar0 * K) + ksw;
  const char* srcA1 = (const char*)(A + (size_t)ar1 * K) + ksw;
  auto bsrc = [&](int nloc) -> const char* {
    int n = n0 + nloc;
    return (const char*)B + ((size_t)(n >> 6) * (K >> 6)) * 8192 + (n & 63) * 128 + ksw;
  };
  const char* srcB0 = bsrc(s0 * 16 + rloc);
  const char* srcB1 = bsrc(s1 * 16 + rloc);

  auto stage = [&](int buf, int k0) {
    int kbA = k0 * 2;
    int kbB = (k0 >> 6) * 8192 + (k0 & 63) * 2;
    gll16(srcA0 + kbA, sm + buf * 8192 + s0 * 1024);
    gll16(srcA1 + kbA, sm + buf * 8192 + s1 * 1024);
    gll16(srcB0 + kbB, sm + 24576 + buf * 8192 + s0 * 1024);
    gll16(srcB1 + kbB, sm + 24576 + buf * 8192 + s1 * 1024);
  };

  int offA[4], offB[4];
#pragma unroll
  for (int i = 0; i < 4; ++i) {
    int ra = wm * 64 + i * 16 + lrow;
    offA[i] = (ra >> 1) * 128 + (((((ra & 1) << 2) + kq) ^ ((ra >> 1) & 7)) << 4);
    int rb = wn * 64 + i * 16 + lrow;
    offB[i] = 24576 + (rb >> 1) * 128 + (((((rb & 1) << 2) + kq) ^ ((rb >> 1) & 7)) << 4);
  }

  ffrag acc[4][4];
#pragma unroll
  for (int i = 0; i < 4; ++i)
#pragma unroll
    for (int j = 0; j < 4; ++j) acc[i][j] = (ffrag){0.f, 0.f, 0.f, 0.f};

  auto compute = [&](int buf) {
    int ab = buf * 8192;
    bfrag a[4], b[4];
#pragma unroll
    for (int i = 0; i < 4; ++i) a[i] = *(const bfrag*)(sm + ab + offA[i]);
#pragma unroll
    for (int j = 0; j < 4; ++j) b[j] = *(const bfrag*)(sm + ab + offB[j]);
#pragma unroll
    for (int i = 0; i < 4; ++i)
#pragma unroll
      for (int j = 0; j < 4; ++j)
        acc[i][j] = __builtin_amdgcn_mfma_f32_16x16x32_bf16(a[i], b[j], acc[i][j], 0, 0, 0);
  };

  stage(0, 0); stage(1, 32);
  asm volatile("s_waitcnt vmcnt(4)" ::: "memory");
  __builtin_amdgcn_s_barrier();

  int nk = K / 32;
  int cur = 0;
  for (int kt = 0; kt < nk; ++kt) {
    int nxt2 = cur + 2; if (nxt2 >= 3) nxt2 -= 3;
    if (kt + 2 < nk) stage(nxt2, (kt + 2) * 32);
    compute(cur);
    if (kt + 1 < nk) {
      if (kt + 2 < nk) { asm volatile("s_waitcnt vmcnt(4)" ::: "memory"); }
      else             { asm volatile("s_waitcnt vmcnt(0)" ::: "memory"); }
    }
    __builtin_amdgcn_s_barrier();
    ++cur; if (cur == 3) cur = 0;
  }

  unsigned short* ht = (unsigned short*)sm;
#pragma unroll
  for (int j = 0; j < 4; ++j) {
    int col = wn * 64 + j * 16 + lrow;
    float bj = bias[n0 + col];
#pragma unroll
    for (int i = 0; i < 4; ++i) {
      int rl = wm * 64 + i * 16 + kq * 4;
#pragma unroll
      for (int r = 0; r < 4; ++r) {
        float v = acc[i][j][r] + bj;
        if (GELU) {
          float z = 1.5957691216f * (v + 0.044715f * v * v * v);
          v = v / (1.0f + __expf(-z));
        }
        ht[(rl + r) * 128 + col] = f2bf(v);
      }
    }
  }
  __syncthreads();
#pragma unroll
  for (int it = 0; it < 8; ++it) {
    int c = it * 256 + tid;
    int row = c >> 4;
    int cc = (c & 15) * 8;
    us8 v = *(const us8*)&ht[row * 128 + cc];
    *(us8*)&out[(size_t)(row0 + row) * N + n0 + cc] = v;
  }
}

// ---------------- combine (y is bf16) ----------------
__global__ __launch_bounds__(256) void combine_kernel(const unsigned short* __restrict__ y,
                                                      const int* __restrict__ row_of,
                                                      const float* __restrict__ topw,
                                                      float* __restrict__ out) {
  int t = blockIdx.x;
  int r0 = row_of[t * 2 + 0], r1 = row_of[t * 2 + 1];
  float w0 = topw[t * 2 + 0], w1 = topw[t * 2 + 1];
  const ushort4* y0 = (const ushort4*)(y + (size_t)r0 * DDIM);
  const ushort4* y1 = (const ushort4*)(y + (size_t)r1 * DDIM);
  float4* o = (float4*)(out + (size_t)t * DDIM);
  int i = threadIdx.x;
  ushort4 a = y0[i], b = y1[i];
  float4 r = { w0 * bf2f(a.x) + w1 * bf2f(b.x), w0 * bf2f(a.y) + w1 * bf2f(b.y),
               w0 * bf2f(a.z) + w1 * bf2f(b.z), w0 * bf2f(a.w) + w1 * bf2f(b.w) };
  o[i] = r;
}

extern "C" void kernel_launch(void* const* d_in, const int* in_sizes, int n_in,
                              void* d_out, int out_size, void* d_ws, size_t ws_size,
                              hipStream_t stream) {
  const float* x  = (const float*)d_in[0];
  const float* Wg = (const float*)d_in[1];
  const float* bg = (const float*)d_in[2];
  const float* W1 = (const float*)d_in[3];
  const float* b1 = (const float*)d_in[4];
  const float* W2 = (const float*)d_in[5];
  const float* b2 = (const float*)d_in[6];
  float* out = (float*)d_out;

  size_t off = 0;
  char* base = (char*)d_ws;
  auto alloc = [&](size_t bytes) -> void* {
    void* p = base + off;
    off += (bytes + 255) & ~(size_t)255;
    return p;
  };
  unsigned short* xb  = (unsigned short*)alloc((size_t)TOK * DDIM * 2);
  unsigned short* w1b = (unsigned short*)alloc((size_t)NEXP * HDIM * DDIM * 2);
  unsigned short* w2b = (unsigned short*)alloc((size_t)NEXP * DDIM * HDIM * 2);
  unsigned short* h   = (unsigned short*)alloc((size_t)CAP * HDIM * 2);
  unsigned short* y   = (unsigned short*)alloc((size_t)CAP * DDIM * 2);
  int*   topi     = (int*)alloc((size_t)TOK * 2 * 4);
  float* topw     = (float*)alloc((size_t)TOK * 2 * 4);
  int*   row_of   = (int*)alloc((size_t)TOK * 2 * 4);
  int*   token_of = (int*)alloc((size_t)CAP * 4);
  int*   cntcur   = (int*)alloc(64);      // cnt = [0..7], cursor = [8..15]
  if (off > ws_size) return;

  int* cnt = cntcur;
  int* cursor = cntcur + 8;

  hipMemsetAsync(cntcur, 0, 64, stream);

  gate_v3<<<256, 256, 0, stream>>>(x, Wg, bg, xb, topi, topw, cnt, token_of);
  transpose_v6<<<2048 + (TOK * 2) / 256, 256, 0, stream>>>(
      W1, w1b, W2, w2b, topi, cnt, cursor, row_of, token_of);

  moe_gemm<true, true><<<dim3(HDIM / 128, CAP / 128), 256, 0, stream>>>(
      xb, w1b, b1, h, HDIM, DDIM, cnt, token_of);
  moe_gemm<false, false><<<dim3(DDIM / 128, CAP / 128), 256, 0, stream>>>(
      h, w2b, b2, y, DDIM, HDIM, cnt, token_of);

  combine_kernel<<<TOK, 256, 0, stream>>>(y, row_of, topw, out);
}

// Round 15
// 531.600 us; speedup vs baseline: 1.0835x; 1.0133x over previous
//
#include <hip/hip_runtime.h>
#include <math.h>

#define TOK   8192
#define DDIM  1024
#define HDIM  4096
#define NEXP  8
#define CAP   17408   /* 16384 + 8*128 pad = 136*128 */

typedef __attribute__((ext_vector_type(8))) short  bfrag;
typedef __attribute__((ext_vector_type(4))) float  ffrag;
typedef __attribute__((ext_vector_type(8))) unsigned short us8;

__device__ __forceinline__ unsigned short f2bf(float f) {
  unsigned int u = __float_as_uint(f);
  u = (u + 0x7FFFu + ((u >> 16) & 1u)) >> 16;   // RNE
  return (unsigned short)u;
}
__device__ __forceinline__ float bf2f(unsigned short u) {
  return __uint_as_float((unsigned int)u << 16);
}

__device__ __forceinline__ void gll16(const void* g, void* l) {
  __builtin_amdgcn_global_load_lds(
      (const __attribute__((address_space(1))) unsigned int*)g,
      (__attribute__((address_space(3))) unsigned int*)l,
      16, 0, 0);
}

// 128-aligned exclusive scan of cnt (uniform, 8 entries)
__device__ __forceinline__ void local_scan(const int* __restrict__ cnt, int* offs) {
  int o = 0;
#pragma unroll
  for (int e = 0; e < NEXP; ++e) {
    offs[e] = o;
    o += ((cnt[e] + 127) >> 7) << 7;
  }
  offs[NEXP] = o;
}

// ---- fused prep: blocks [0,256) gate; blocks [256,2304) weight transpose ----
// Gate and transpose are independent; fusing overlaps their execution.
__global__ __launch_bounds__(256)
void prep_kernel(const float* __restrict__ x,  const float* __restrict__ Wg,
                 const float* __restrict__ bg, unsigned short* __restrict__ xb,
                 int* __restrict__ topi, float* __restrict__ topw,
                 int* __restrict__ cnt, int* __restrict__ token_of,
                 const float* __restrict__ W1, unsigned short* __restrict__ w1b,
                 const float* __restrict__ W2, unsigned short* __restrict__ w2b) {
  __shared__ __align__(16) float T[2 * 4352];   // transpose dbuf; gate aliases hist
  int tid = threadIdx.x;

  if (blockIdx.x < 256) {
    // ---------------- gate path (r12 gate_v3, unchanged logic) ----------------
    int* hist = (int*)T;
    if (tid < NEXP) hist[tid] = 0;
    int gid = blockIdx.x * 256 + tid;
    if (gid < CAP) token_of[gid] = -1;
    __syncthreads();

    int w = tid >> 6, l = tid & 63;
    const float4* wg4 = (const float4*)Wg;
#pragma unroll 1
    for (int ti = 0; ti < 8; ++ti) {
      int t = (blockIdx.x * 4 + w) * 8 + ti;
      const float4* xr = (const float4*)(x + (size_t)t * DDIM);
      float acc[8];
#pragma unroll
      for (int e = 0; e < 8; ++e) acc[e] = 0.f;
#pragma unroll
      for (int gi = 0; gi < 2; ++gi) {
        int f = gi * 128 + 2 * l;
        float4 a0 = xr[f], a1 = xr[f + 1];
        us8 o;
        o[0] = (short)f2bf(a0.x); o[1] = (short)f2bf(a0.y);
        o[2] = (short)f2bf(a0.z); o[3] = (short)f2bf(a0.w);
        o[4] = (short)f2bf(a1.x); o[5] = (short)f2bf(a1.y);
        o[6] = (short)f2bf(a1.z); o[7] = (short)f2bf(a1.w);
        *(us8*)&xb[(size_t)t * DDIM + f * 4] = o;
        float xs[8] = { a0.x, a0.y, a0.z, a0.w, a1.x, a1.y, a1.z, a1.w };
        int dbase = f * 4;
#pragma unroll
        for (int c = 0; c < 8; ++c) {
          float4 w0 = wg4[(dbase + c) * 2 + 0];
          float4 w1 = wg4[(dbase + c) * 2 + 1];
          acc[0] += xs[c] * w0.x; acc[1] += xs[c] * w0.y;
          acc[2] += xs[c] * w0.z; acc[3] += xs[c] * w0.w;
          acc[4] += xs[c] * w1.x; acc[5] += xs[c] * w1.y;
          acc[6] += xs[c] * w1.z; acc[7] += xs[c] * w1.w;
        }
      }
#pragma unroll
      for (int off = 32; off >= 1; off >>= 1)
#pragma unroll
        for (int e = 0; e < 8; ++e) acc[e] += __shfl_down(acc[e], off);
      if (l == 0) {
        float v[8];
#pragma unroll
        for (int e = 0; e < 8; ++e) v[e] = acc[e] + bg[e];
        int i0 = 0;
#pragma unroll
        for (int e = 1; e < 8; ++e) if (v[e] > v[i0]) i0 = e;
        int i1 = -1;
#pragma unroll
        for (int e = 0; e < 8; ++e) if (e != i0 && (i1 < 0 || v[e] > v[i1])) i1 = e;
        float e1 = expf(v[i1] - v[i0]);
        float s = 1.f + e1;
        topi[t * 2 + 0] = i0; topi[t * 2 + 1] = i1;
        topw[t * 2 + 0] = 1.f / s; topw[t * 2 + 1] = e1 / s;
        atomicAdd(&hist[i0], 1);
        atomicAdd(&hist[i1], 1);
      }
    }
    __syncthreads();
    if (tid < NEXP) atomicAdd(&cnt[tid], hist[tid]);
    return;
  }

  // ---------------- transpose path (r14 v6, unchanged logic) ----------------
  int orig = blockIdx.x - 256;
  int bid = (orig & 7) * 256 + (orig >> 3);    // XCD-chunked, bijective
  const float* in; unsigned short* out; int R, C, tile;
  if (bid < 1024) { in = W1; out = w1b; R = DDIM; C = HDIM; tile = bid; }
  else            { in = W2; out = w2b; R = HDIM; C = DDIM; tile = bid - 1024; }
  int e = tile >> 7;
  int t = tile & 127;
  int tpr = C >> 8;
  int ty = t / tpr, tx = t % tpr;
  size_t bo = (size_t)e * R * C;
  in += bo; out += bo;
  int r0 = ty * 128, c0 = tx * 256;

  int r4 = (tid >> 4) * 4;
  int c4 = (tid & 15) * 4;
  int oc = tid >> 2;
  int kg = (tid & 3) * 16;

  auto ld = [&](int s, float4* v) {
    int rb = r0 + (s >> 2) * 64;
    int cb = c0 + (s & 3) * 64;
    v[0] = *(const float4*)&in[(size_t)(rb + r4 + 0) * C + cb + c4];
    v[1] = *(const float4*)&in[(size_t)(rb + r4 + 1) * C + cb + c4];
    v[2] = *(const float4*)&in[(size_t)(rb + r4 + 2) * C + cb + c4];
    v[3] = *(const float4*)&in[(size_t)(rb + r4 + 3) * C + cb + c4];
  };

  float4 v[4], nv[4];
  ld(0, v);
#pragma unroll
  for (int s = 0; s < 8; ++s) {
    if (s + 1 < 8) ld(s + 1, nv);
    float* Tb = T + (s & 1) * 4352;
    int rb = r0 + (s >> 2) * 64;
    int cb = c0 + (s & 3) * 64;
    float4 t0 = { v[0].x, v[1].x, v[2].x, v[3].x };
    float4 t1 = { v[0].y, v[1].y, v[2].y, v[3].y };
    float4 t2 = { v[0].z, v[1].z, v[2].z, v[3].z };
    float4 t3 = { v[0].w, v[1].w, v[2].w, v[3].w };
    *(float4*)&Tb[(c4 + 0) * 68 + r4] = t0;
    *(float4*)&Tb[(c4 + 1) * 68 + r4] = t1;
    *(float4*)&Tb[(c4 + 2) * 68 + r4] = t2;
    *(float4*)&Tb[(c4 + 3) * 68 + r4] = t3;
    __syncthreads();
    float4 f0 = *(const float4*)&Tb[oc * 68 + kg + 0];
    float4 f1 = *(const float4*)&Tb[oc * 68 + kg + 4];
    float4 f2 = *(const float4*)&Tb[oc * 68 + kg + 8];
    float4 f3 = *(const float4*)&Tb[oc * 68 + kg + 12];
    us8 a, b;
    a[0] = (short)f2bf(f0.x); a[1] = (short)f2bf(f0.y);
    a[2] = (short)f2bf(f0.z); a[3] = (short)f2bf(f0.w);
    a[4] = (short)f2bf(f1.x); a[5] = (short)f2bf(f1.y);
    a[6] = (short)f2bf(f1.z); a[7] = (short)f2bf(f1.w);
    b[0] = (short)f2bf(f2.x); b[1] = (short)f2bf(f2.y);
    b[2] = (short)f2bf(f2.z); b[3] = (short)f2bf(f2.w);
    b[4] = (short)f2bf(f3.x); b[5] = (short)f2bf(f3.y);
    b[6] = (short)f2bf(f3.z); b[7] = (short)f2bf(f3.w);
    size_t sub = ((size_t)(cb >> 6) * (R >> 6) + (rb >> 6)) * 4096;
    *(us8*)&out[sub + oc * 64 + kg + 0] = a;
    *(us8*)&out[sub + oc * 64 + kg + 8] = b;
    v[0] = nv[0]; v[1] = nv[1]; v[2] = nv[2]; v[3] = nv[3];
  }
}

// ---------------- assign rows (needs gate complete) ----------------
__global__ __launch_bounds__(256) void assign_kernel(const int* __restrict__ topi,
                                                     const int* __restrict__ cnt,
                                                     int* __restrict__ cursor,
                                                     int* __restrict__ row_of,
                                                     int* __restrict__ token_of) {
  int offs[NEXP + 1];
  local_scan(cnt, offs);
  int id = blockIdx.x * 256 + threadIdx.x;
  int e = topi[id];
  int slot = atomicAdd(&cursor[e], 1);
  int row = offs[e] + slot;
  row_of[id] = row;
  token_of[row] = id >> 1;
}

// ---- grouped GEMM (r12 structure): 128^2, 3-buf counted-vmcnt, blocked B ----
// KSPLIT: grid (16,136); bx LSB = K-half; partials to out + kp*CAP*N (bias in
// half 0 only). Inner loop/LDS/swizzle identical to the proven r12 kernel.
template<bool INDIRECT, bool GELU, bool KSPLIT>
__global__ __launch_bounds__(256)
void moe_gemm(const unsigned short* __restrict__ A,
              const unsigned short* __restrict__ B0,
              const float* __restrict__ bias0,
              unsigned short* __restrict__ out,
              int N, int Kfull,
              const int* __restrict__ cnt,
              const int* __restrict__ token_of) {
  int offsets[NEXP + 1];
  local_scan(cnt, offsets);

  int nwg = gridDim.x * gridDim.y;
  int orig = blockIdx.y * gridDim.x + blockIdx.x;
  int V = nwg >> 3;
  int vid = (orig & 7) * V + (orig >> 3);
  int xcd = vid / V;
  int vloc = vid - xcd * V;
  int P = V / gridDim.x;
  int CW = gridDim.x >= 8 ? 8 : gridDim.x;
  int per = P * CW;
  int g = vloc / per;
  int rem = vloc - g * per;
  int m = rem / CW;
  int bx = g * CW + (rem - m * CW);
  int by = xcd * P + m;

  int kp = 0, koff = 0, Klocal = Kfull;
  if (KSPLIT) {
    kp = bx & 1; bx >>= 1;
    Klocal = Kfull >> 1;
    koff = kp * Klocal;
    out += (size_t)kp * CAP * N;
  }

  int row0 = by * 128;
  if (row0 >= offsets[NEXP]) return;
  int e = 0;
  while (row0 >= offsets[e + 1]) ++e;
  const unsigned short* B = B0 + (size_t)e * N * Kfull;
  const float* bias = bias0 + (size_t)e * N;
  int n0 = bx * 128;

  __shared__ __align__(16) char sm[49152];

  int tid = threadIdx.x;
  int w = tid >> 6, l = tid & 63;
  int lrow = l & 15, kq = l >> 4;
  int wm = w >> 1, wn = w & 1;

  int c2 = (l & 7) ^ (l >> 3);
  int rloc = ((l >> 3) << 1) + (c2 >> 2);
  int ksw = (c2 & 3) * 16;
  int s0 = 2 * w, s1 = 2 * w + 1;

  int gr0 = row0 + s0 * 16 + rloc, gr1 = row0 + s1 * 16 + rloc;
  int ar0, ar1;
  if (INDIRECT) {
    int t0 = token_of[gr0]; ar0 = t0 < 0 ? 0 : t0;
    int t1 = token_of[gr1]; ar1 = t1 < 0 ? 0 : t1;
  } else { ar0 = gr0; ar1 = gr1; }
  const char* srcA0 = (const char*)(A + (size_t)ar0 * Kfull + koff) + ksw;
  const char* srcA1 = (const char*)(A + (size_t)ar1 * Kfull + koff) + ksw;
  auto bsrc = [&](int nloc) -> const char* {
    int n = n0 + nloc;
    return (const char*)B + ((size_t)(n >> 6) * (Kfull >> 6) + (koff >> 6)) * 8192
         + (n & 63) * 128 + ksw;
  };
  const char* srcB0 = bsrc(s0 * 16 + rloc);
  const char* srcB1 = bsrc(s1 * 16 + rloc);

  auto stage = [&](int buf, int k0) {        // k0 relative to koff, mult of 32
    int kbA = k0 * 2;
    int kbB = (k0 >> 6) * 8192 + (k0 & 63) * 2;
    gll16(srcA0 + kbA, sm + buf * 8192 + s0 * 1024);
    gll16(srcA1 + kbA, sm + buf * 8192 + s1 * 1024);
    gll16(srcB0 + kbB, sm + 24576 + buf * 8192 + s0 * 1024);
    gll16(srcB1 + kbB, sm + 24576 + buf * 8192 + s1 * 1024);
  };

  int offA[4], offB[4];
#pragma unroll
  for (int i = 0; i < 4; ++i) {
    int ra = wm * 64 + i * 16 + lrow;
    offA[i] = (ra >> 1) * 128 + (((((ra & 1) << 2) + kq) ^ ((ra >> 1) & 7)) << 4);
    int rb = wn * 64 + i * 16 + lrow;
    offB[i] = 24576 + (rb >> 1) * 128 + (((((rb & 1) << 2) + kq) ^ ((rb >> 1) & 7)) << 4);
  }

  ffrag acc[4][4];
#pragma unroll
  for (int i = 0; i < 4; ++i)
#pragma unroll
    for (int j = 0; j < 4; ++j) acc[i][j] = (ffrag){0.f, 0.f, 0.f, 0.f};

  auto compute = [&](int buf) {
    int ab = buf * 8192;
    bfrag a[4], b[4];
#pragma unroll
    for (int i = 0; i < 4; ++i) a[i] = *(const bfrag*)(sm + ab + offA[i]);
#pragma unroll
    for (int j = 0; j < 4; ++j) b[j] = *(const bfrag*)(sm + ab + offB[j]);
#pragma unroll
    for (int i = 0; i < 4; ++i)
#pragma unroll
      for (int j = 0; j < 4; ++j)
        acc[i][j] = __builtin_amdgcn_mfma_f32_16x16x32_bf16(a[i], b[j], acc[i][j], 0, 0, 0);
  };

  stage(0, 0); stage(1, 32);
  asm volatile("s_waitcnt vmcnt(4)" ::: "memory");
  __builtin_amdgcn_s_barrier();

  int nk = Klocal / 32;
  int cur = 0;
  for (int kt = 0; kt < nk; ++kt) {
    int nxt2 = cur + 2; if (nxt2 >= 3) nxt2 -= 3;
    if (kt + 2 < nk) stage(nxt2, (kt + 2) * 32);
    compute(cur);
    if (kt + 1 < nk) {
      if (kt + 2 < nk) { asm volatile("s_waitcnt vmcnt(4)" ::: "memory"); }
      else             { asm volatile("s_waitcnt vmcnt(0)" ::: "memory"); }
    }
    __builtin_amdgcn_s_barrier();
    ++cur; if (cur == 3) cur = 0;
  }

  unsigned short* ht = (unsigned short*)sm;
#pragma unroll
  for (int j = 0; j < 4; ++j) {
    int col = wn * 64 + j * 16 + lrow;
    float bj = (!KSPLIT || kp == 0) ? bias[n0 + col] : 0.0f;
#pragma unroll
    for (int i = 0; i < 4; ++i) {
      int rl = wm * 64 + i * 16 + kq * 4;
#pragma unroll
      for (int r = 0; r < 4; ++r) {
        float v = acc[i][j][r] + bj;
        if (GELU) {
          float z = 1.5957691216f * (v + 0.044715f * v * v * v);
          v = v / (1.0f + __expf(-z));
        }
        ht[(rl + r) * 128 + col] = f2bf(v);
      }
    }
  }
  __syncthreads();
#pragma unroll
  for (int it = 0; it < 8; ++it) {
    int c = it * 256 + tid;
    int row = c >> 4;
    int cc = (c & 15) * 8;
    us8 v = *(const us8*)&ht[row * 128 + cc];
    *(us8*)&out[(size_t)(row0 + row) * N + n0 + cc] = v;
  }
}

// -------- combine: sum two bf16 K-partials, weight, accumulate fp32 --------
__global__ __launch_bounds__(256) void combine_kernel(const unsigned short* __restrict__ y,
                                                      const int* __restrict__ row_of,
                                                      const float* __restrict__ topw,
                                                      float* __restrict__ out) {
  int t = blockIdx.x;
  int r0 = row_of[t * 2 + 0], r1 = row_of[t * 2 + 1];
  float w0 = topw[t * 2 + 0], w1 = topw[t * 2 + 1];
  const size_t P1 = (size_t)CAP * DDIM;
  const ushort4* a0 = (const ushort4*)(y + (size_t)r0 * DDIM);
  const ushort4* a1 = (const ushort4*)(y + P1 + (size_t)r0 * DDIM);
  const ushort4* b0 = (const ushort4*)(y + (size_t)r1 * DDIM);
  const ushort4* b1 = (const ushort4*)(y + P1 + (size_t)r1 * DDIM);
  float4* o = (float4*)(out + (size_t)t * DDIM);
  int i = threadIdx.x;
  ushort4 pa0 = a0[i], pa1 = a1[i], pb0 = b0[i], pb1 = b1[i];
  float4 r = {
    w0 * (bf2f(pa0.x) + bf2f(pa1.x)) + w1 * (bf2f(pb0.x) + bf2f(pb1.x)),
    w0 * (bf2f(pa0.y) + bf2f(pa1.y)) + w1 * (bf2f(pb0.y) + bf2f(pb1.y)),
    w0 * (bf2f(pa0.z) + bf2f(pa1.z)) + w1 * (bf2f(pb0.z) + bf2f(pb1.z)),
    w0 * (bf2f(pa0.w) + bf2f(pa1.w)) + w1 * (bf2f(pb0.w) + bf2f(pb1.w))
  };
  o[i] = r;
}

extern "C" void kernel_launch(void* const* d_in, const int* in_sizes, int n_in,
                              void* d_out, int out_size, void* d_ws, size_t ws_size,
                              hipStream_t stream) {
  const float* x  = (const float*)d_in[0];
  const float* Wg = (const float*)d_in[1];
  const float* bg = (const float*)d_in[2];
  const float* W1 = (const float*)d_in[3];
  const float* b1 = (const float*)d_in[4];
  const float* W2 = (const float*)d_in[5];
  const float* b2 = (const float*)d_in[6];
  float* out = (float*)d_out;

  size_t off = 0;
  char* base = (char*)d_ws;
  auto alloc = [&](size_t bytes) -> void* {
    void* p = base + off;
    off += (bytes + 255) & ~(size_t)255;
    return p;
  };
  unsigned short* xb  = (unsigned short*)alloc((size_t)TOK * DDIM * 2);
  unsigned short* w1b = (unsigned short*)alloc((size_t)NEXP * HDIM * DDIM * 2);
  unsigned short* w2b = (unsigned short*)alloc((size_t)NEXP * DDIM * HDIM * 2);
  unsigned short* h   = (unsigned short*)alloc((size_t)CAP * HDIM * 2);
  unsigned short* y   = (unsigned short*)alloc((size_t)2 * CAP * DDIM * 2);
  int*   topi     = (int*)alloc((size_t)TOK * 2 * 4);
  float* topw     = (float*)alloc((size_t)TOK * 2 * 4);
  int*   row_of   = (int*)alloc((size_t)TOK * 2 * 4);
  int*   token_of = (int*)alloc((size_t)CAP * 4);
  int*   cntcur   = (int*)alloc(64);      // cnt = [0..7], cursor = [8..15]
  if (off > ws_size) return;

  int* cnt = cntcur;
  int* cursor = cntcur + 8;

  hipMemsetAsync(cntcur, 0, 64, stream);

  prep_kernel<<<2304, 256, 0, stream>>>(x, Wg, bg, xb, topi, topw, cnt, token_of,
                                        W1, w1b, W2, w2b);
  assign_kernel<<<(TOK * 2) / 256, 256, 0, stream>>>(topi, cnt, cursor,
                                                     row_of, token_of);

  moe_gemm<true, true, false><<<dim3(HDIM / 128, CAP / 128), 256, 0, stream>>>(
      xb, w1b, b1, h, HDIM, DDIM, cnt, token_of);
  moe_gemm<false, false, true><<<dim3(16, CAP / 128), 256, 0, stream>>>(
      h, w2b, b2, y, DDIM, HDIM, cnt, token_of);

  combine_kernel<<<TOK, 256, 0, stream>>>(y, row_of, topw, out);
}